// Round 1
// baseline (587.259 us; speedup 1.0000x reference)
//
#include <hip/hip_runtime.h>
#include <hip/hip_bf16.h>
#include <math.h>

// Problem constants (reference: B,C,H,W = 32,64,64,64; K=1024)
constexpr int Bc  = 32;
constexpr int Cc  = 64;
constexpr int Hc  = 64;
constexpr int Wc  = 64;
constexpr int Kc  = 1024;
constexpr int HW  = Hc * Wc;          // 4096
constexpr int Nrows = Bc * HW;        // 131072 rows of dim C
constexpr int CHW = Cc * HW;          // 262144
constexpr int TOTAL = Bc * CHW;       // 8388608 elements of q_out

// ---------------------------------------------------------------------------
// Kernel 1: e2[k] = ||codebook[k]||^2.  One wave per code.
// ---------------------------------------------------------------------------
__global__ void e2_kernel(const float* __restrict__ cb, float* __restrict__ e2) {
    int k = blockIdx.x;                       // 0..1023
    float v = cb[k * Cc + threadIdx.x];       // coalesced 64 floats
    float s = v * v;
    #pragma unroll
    for (int off = 32; off; off >>= 1) s += __shfl_down(s, off);
    if (threadIdx.x == 0) e2[k] = s;
}

// ---------------------------------------------------------------------------
// Kernel 2 (main): one thread per row.
//  - load x[64] into VGPRs (coalesced: lanes = consecutive hw)
//  - scan all K codes; codebook row address is wave-uniform -> scalar/broadcast
//    loads, no LDS; 4 independent FMA chains for ILP
//  - argmin with strict < (first min wins, matches numpy tie-break)
//  - epilogue: write q_out (coalesced over hw), accumulate SSE, histogram
// ---------------------------------------------------------------------------
__global__ __launch_bounds__(256) void vq_main(
        const float* __restrict__ inp,   // [B,C,H,W]
        const float* __restrict__ cb,    // [K,C]
        const float* __restrict__ e2,    // [K]
        float* __restrict__ qout,        // [B,C,H,W] (d_out + 1)
        unsigned int* __restrict__ counts,
        float* __restrict__ sse_out) {
    int t  = blockIdx.x * 256 + threadIdx.x;  // 0..131071
    int b  = t >> 12;                          // / 4096
    int hw = t & 4095;
    const float* xp = inp + b * CHW + hw;

    float x[Cc];
    #pragma unroll
    for (int c = 0; c < Cc; ++c) x[c] = xp[c * HW];

    float best = 3.4e38f;
    int bidx = 0;
    #pragma unroll 2
    for (int k = 0; k < Kc; ++k) {
        const float4* ep = reinterpret_cast<const float4*>(cb + (k << 6));
        float d0 = 0.f, d1 = 0.f, d2 = 0.f, d3 = 0.f;
        #pragma unroll
        for (int c4 = 0; c4 < 16; ++c4) {
            float4 e = ep[c4];
            d0 = fmaf(x[4 * c4 + 0], e.x, d0);
            d1 = fmaf(x[4 * c4 + 1], e.y, d1);
            d2 = fmaf(x[4 * c4 + 2], e.z, d2);
            d3 = fmaf(x[4 * c4 + 3], e.w, d3);
        }
        float d = e2[k] - 2.0f * ((d0 + d1) + (d2 + d3));
        if (d < best) { best = d; bidx = k; }
    }

    // histogram
    atomicAdd(&counts[bidx], 1u);

    // epilogue: gather chosen code, write transposed output, SSE
    const float* qv = cb + (bidx << 6);
    float* op = qout + b * CHW + hw;
    float s0 = 0.f, s1 = 0.f, s2 = 0.f, s3 = 0.f;
    #pragma unroll
    for (int c4 = 0; c4 < 16; ++c4) {
        float q0 = qv[4 * c4 + 0];
        float q1 = qv[4 * c4 + 1];
        float q2 = qv[4 * c4 + 2];
        float q3 = qv[4 * c4 + 3];
        float e0 = q0 - x[4 * c4 + 0];
        float e1 = q1 - x[4 * c4 + 1];
        float e2v = q2 - x[4 * c4 + 2];
        float e3 = q3 - x[4 * c4 + 3];
        s0 = fmaf(e0, e0, s0);
        s1 = fmaf(e1, e1, s1);
        s2 = fmaf(e2v, e2v, s2);
        s3 = fmaf(e3, e3, s3);
        op[(4 * c4 + 0) * HW] = q0;
        op[(4 * c4 + 1) * HW] = q1;
        op[(4 * c4 + 2) * HW] = q2;
        op[(4 * c4 + 3) * HW] = q3;
    }
    float sse = (s0 + s1) + (s2 + s3);
    #pragma unroll
    for (int off = 32; off; off >>= 1) sse += __shfl_down(sse, off);
    if ((threadIdx.x & 63) == 0) atomicAdd(sse_out, sse);
}

// ---------------------------------------------------------------------------
// Kernel 3: finalize loss + perplexity. Single block of 1024 threads.
// ---------------------------------------------------------------------------
__global__ void finalize_kernel(const unsigned int* __restrict__ counts,
                                const float* __restrict__ sse,
                                const float* __restrict__ beta,
                                float* __restrict__ loss_out,
                                float* __restrict__ perp_out) {
    __shared__ float red[16];
    int t = threadIdx.x;                  // 0..1023 == K
    float p = (float)counts[t] * (1.0f / (float)Nrows);
    float s = p * logf(p + 1e-10f);
    #pragma unroll
    for (int off = 32; off; off >>= 1) s += __shfl_down(s, off);
    if ((t & 63) == 0) red[t >> 6] = s;
    __syncthreads();
    if (t == 0) {
        float tot = 0.f;
        #pragma unroll
        for (int i = 0; i < 16; ++i) tot += red[i];
        *perp_out = expf(-tot);
        *loss_out = (1.0f + *beta) * (*sse) * (1.0f / (float)TOTAL);
    }
}

// ---------------------------------------------------------------------------
extern "C" void kernel_launch(void* const* d_in, const int* in_sizes, int n_in,
                              void* d_out, int out_size, void* d_ws, size_t ws_size,
                              hipStream_t stream) {
    const float* inp  = (const float*)d_in[0];   // [32,64,64,64]
    const float* cb   = (const float*)d_in[1];   // [1024,64]
    const float* beta = (const float*)d_in[2];   // scalar

    float* loss = (float*)d_out;                 // [0]
    float* qout = loss + 1;                      // [1 .. 8388608]
    float* perp = loss + 1 + TOTAL;              // [8388609]

    float* wsf = (float*)d_ws;
    float* e2v = wsf;                            // 1024 floats
    unsigned int* counts = (unsigned int*)(wsf + Kc);  // 1024 u32
    float* sse = wsf + 2 * Kc;                   // 1 float

    // zero counts + sse (+ e2, harmless; ws is re-poisoned each launch)
    hipMemsetAsync(d_ws, 0, (2 * Kc + 1) * sizeof(float), stream);

    e2_kernel<<<Kc, 64, 0, stream>>>(cb, e2v);
    vq_main<<<Nrows / 256, 256, 0, stream>>>(inp, cb, e2v, qout, counts, sse);
    finalize_kernel<<<1, Kc, 0, stream>>>(counts, sse, beta, loss, perp);
}

// Round 2
// 152.920 us; speedup vs baseline: 3.8403x; 3.8403x over previous
//
#include <hip/hip_runtime.h>
#include <math.h>

// Problem constants: B,C,H,W = 32,64,64,64; K=1024
constexpr int Bc  = 32;
constexpr int Cc  = 64;
constexpr int Kc  = 1024;
constexpr int HW  = 64 * 64;          // 4096
constexpr int CHW = Cc * HW;          // 262144
constexpr int Nrows = Bc * HW;        // 131072
constexpr int TOTAL = Bc * CHW;       // 8388608

typedef __attribute__((ext_vector_type(8))) short short8;   // 8 bf16 = 4 VGPRs
typedef __attribute__((ext_vector_type(4))) float f32x4;

__device__ __forceinline__ unsigned short bf16_rne(float x) {
    unsigned u = __float_as_uint(x);
    return (unsigned short)((u + 0x7FFFu + ((u >> 16) & 1u)) >> 16);
}

union U4S8 { uint4 u; short8 s; };

// ---------------------------------------------------------------------------
// Prep: e2p[k] = 1 + ||e_k||^2 ; codebook -> bf16 in B-fragment order:
//   cbB[((ct*2+ks)*64 + quad*16 + n)*8 + j] = bf16(cb[ct*16+n][ks*32+quad*8+j])
// so the main loop's B load is uint4 at (tile*64 + lane)*16 bytes: fully
// coalesced 1 KB per wave instruction.
// ---------------------------------------------------------------------------
__global__ void prep_kernel(const float* __restrict__ cb,
                            float* __restrict__ e2p,
                            unsigned short* __restrict__ cbB) {
    int k = blockIdx.x;          // code 0..1023
    int c = threadIdx.x;         // dim  0..63
    float v = cb[k * Cc + c];
    float s = v * v;
    #pragma unroll
    for (int off = 32; off; off >>= 1) s += __shfl_down(s, off);
    if (c == 0) e2p[k] = 1.0f + s;

    int ct = k >> 4, n = k & 15;
    int ks = c >> 5, quad = (c >> 3) & 3, j = c & 7;
    cbB[(((ct * 2 + ks) * 64) + quad * 16 + n) * 8 + j] = bf16_rne(v);
}

// ---------------------------------------------------------------------------
// Main: 512 blocks x 256 threads. Block = 256 consecutive rows (same b).
// Stage X-tile to LDS (bf16, XOR-swizzled 16B chunks), each wave computes
// S = X(64 rows) x E^T(1024 codes) via mfma_f32_16x16x32_bf16, argmin fused
// with index packed into the low 10 mantissa bits of d' = 1 + ||e||^2 - 2x.e
// (d' in (0.5,2) => positive, uint order == float order).
// ---------------------------------------------------------------------------
__global__ __launch_bounds__(256) void vq_main(
        const float* __restrict__ inp,
        const float* __restrict__ cb,        // fp32 codebook (epilogue gather)
        const float* __restrict__ e2p,
        const uint4* __restrict__ cbB4,      // bf16 codebook, B-frag order
        float* __restrict__ qout,
        unsigned int* __restrict__ counts,
        float* __restrict__ sse_out) {
    __shared__ uint4 lds_a[256 * 8];        // 32 KB: 256 rows x 8 chunks(16B)
    __shared__ float lds_e2p[Kc];           // 4 KB
    __shared__ unsigned lds_res[256];       // 1 KB

    const int tid = threadIdx.x;
    const int b   = blockIdx.x >> 4;        // 16 blocks per batch image
    const int hw0 = (blockIdx.x & 15) << 8; // 256 hw per block
    const float* xp = inp + b * CHW + hw0 + tid;

    // ---- stage A (transpose [c][hw] -> [row][c] bf16) + ||x||^2 ----
    float x2 = 0.f;
    uint2* la2 = (uint2*)lds_a;
    #pragma unroll
    for (int c4 = 0; c4 < 16; ++c4) {
        float v0 = xp[(4 * c4 + 0) * HW];
        float v1 = xp[(4 * c4 + 1) * HW];
        float v2 = xp[(4 * c4 + 2) * HW];
        float v3 = xp[(4 * c4 + 3) * HW];
        x2 = fmaf(v0, v0, x2); x2 = fmaf(v1, v1, x2);
        x2 = fmaf(v2, v2, x2); x2 = fmaf(v3, v3, x2);
        uint2 p;
        p.x = (unsigned)bf16_rne(v0) | ((unsigned)bf16_rne(v1) << 16);
        p.y = (unsigned)bf16_rne(v2) | ((unsigned)bf16_rne(v3) << 16);
        int ch = c4 >> 1;
        int sw = ch ^ (tid & 7);
        la2[tid * 16 + sw * 2 + (c4 & 1)] = p;
    }
    #pragma unroll
    for (int i = 0; i < 4; ++i) lds_e2p[tid + 256 * i] = e2p[tid + 256 * i];
    __syncthreads();

    const int lane = tid & 63, w = tid >> 6;
    const int col = lane & 15, quad = lane >> 4;

    // ---- A fragments: wave w owns rows w*64 .. w*64+63 ----
    short8 af[4][2];
    #pragma unroll
    for (int mi = 0; mi < 4; ++mi) {
        #pragma unroll
        for (int ks = 0; ks < 2; ++ks) {
            int row = w * 64 + mi * 16 + col;
            int sw = (ks * 4 + quad) ^ (row & 7);
            U4S8 t; t.u = lds_a[row * 8 + sw];
            af[mi][ks] = t.s;
        }
    }

    unsigned best[4][4];
    #pragma unroll
    for (int mi = 0; mi < 4; ++mi)
        #pragma unroll
        for (int e = 0; e < 4; ++e) best[mi][e] = 0xFFFFFFFFu;

    // ---- main loop over 64 code tiles (16 codes each) ----
    uint4 nb0 = cbB4[lane];
    uint4 nb1 = cbB4[64 + lane];
    #pragma unroll 2
    for (int ct = 0; ct < 64; ++ct) {
        U4S8 t0, t1; t0.u = nb0; t1.u = nb1;
        float e2v = lds_e2p[ct * 16 + col];
        if (ct < 63) {
            nb0 = cbB4[(ct + 1) * 128 + lane];
            nb1 = cbB4[(ct + 1) * 128 + 64 + lane];
        }
        unsigned code = (unsigned)(ct * 16 + col);
        #pragma unroll
        for (int mi = 0; mi < 4; ++mi) {
            f32x4 acc = {0.f, 0.f, 0.f, 0.f};
            acc = __builtin_amdgcn_mfma_f32_16x16x32_bf16(af[mi][0], t0.s, acc, 0, 0, 0);
            acc = __builtin_amdgcn_mfma_f32_16x16x32_bf16(af[mi][1], t1.s, acc, 0, 0, 0);
            #pragma unroll
            for (int e = 0; e < 4; ++e) {
                float d = fmaf(-2.0f, acc[e], e2v);     // d' = 1 + e2 - 2x.e
                unsigned p = (__float_as_uint(d) & 0xFFFFFC00u) | code;
                best[mi][e] = best[mi][e] < p ? best[mi][e] : p;
            }
        }
    }

    // ---- cross-lane argmin over the 16 cols; write per-row result ----
    #pragma unroll
    for (int mi = 0; mi < 4; ++mi) {
        #pragma unroll
        for (int e = 0; e < 4; ++e) {
            unsigned v = best[mi][e];
            #pragma unroll
            for (int m = 1; m < 16; m <<= 1) {
                unsigned o = (unsigned)__shfl_xor((int)v, m);
                v = v < o ? v : o;
            }
            if (col == e) lds_res[w * 64 + mi * 16 + quad * 4 + e] = v;
        }
    }
    __syncthreads();

    // ---- epilogue: thread tid owns row tid again ----
    unsigned pk = lds_res[tid];
    int idx = (int)(pk & 1023u);
    float dmin = __uint_as_float(pk & 0xFFFFFC00u) - 1.0f;
    float sse = x2 + dmin;                  // ||x||^2 + (e2 - 2x.e) = ||x-e||^2
    atomicAdd(&counts[idx], 1u);

    const float4* qv = (const float4*)(cb + idx * Cc);
    float* op = qout + b * CHW + hw0 + tid;
    #pragma unroll
    for (int c4 = 0; c4 < 16; ++c4) {
        float4 q = qv[c4];
        op[(4 * c4 + 0) * HW] = q.x;
        op[(4 * c4 + 1) * HW] = q.y;
        op[(4 * c4 + 2) * HW] = q.z;
        op[(4 * c4 + 3) * HW] = q.w;
    }
    #pragma unroll
    for (int off = 32; off; off >>= 1) sse += __shfl_down(sse, off);
    if (lane == 0) atomicAdd(sse_out, sse);
}

// ---------------------------------------------------------------------------
__global__ void finalize_kernel(const unsigned int* __restrict__ counts,
                                const float* __restrict__ sse,
                                const float* __restrict__ beta,
                                float* __restrict__ loss_out,
                                float* __restrict__ perp_out) {
    __shared__ float red[16];
    int t = threadIdx.x;                  // 0..1023 == K
    float p = (float)counts[t] * (1.0f / (float)Nrows);
    float s = p * logf(p + 1e-10f);
    #pragma unroll
    for (int off = 32; off; off >>= 1) s += __shfl_down(s, off);
    if ((t & 63) == 0) red[t >> 6] = s;
    __syncthreads();
    if (t == 0) {
        float tot = 0.f;
        #pragma unroll
        for (int i = 0; i < 16; ++i) tot += red[i];
        *perp_out = expf(-tot);
        *loss_out = (1.0f + *beta) * (*sse) * (1.0f / (float)TOTAL);
    }
}

// ---------------------------------------------------------------------------
// Workspace layout (bytes):
//   [0, 4096)        counts (1024 u32)
//   [4096, 4100)     sse (1 f32)
//   [8192, 12288)    e2p (1024 f32)
//   [12288, 143360)  cbB bf16 B-frag order (64K ushorts)
// ---------------------------------------------------------------------------
extern "C" void kernel_launch(void* const* d_in, const int* in_sizes, int n_in,
                              void* d_out, int out_size, void* d_ws, size_t ws_size,
                              hipStream_t stream) {
    const float* inp  = (const float*)d_in[0];
    const float* cb   = (const float*)d_in[1];
    const float* beta = (const float*)d_in[2];

    float* loss = (float*)d_out;
    float* qout = loss + 1;
    float* perp = loss + 1 + TOTAL;

    char* ws = (char*)d_ws;
    unsigned int* counts = (unsigned int*)ws;
    float* sse  = (float*)(ws + 4096);
    float* e2p  = (float*)(ws + 8192);
    unsigned short* cbB = (unsigned short*)(ws + 12288);

    hipMemsetAsync(d_ws, 0, 4100, stream);  // counts + sse

    prep_kernel<<<Kc, 64, 0, stream>>>(cb, e2p, cbB);
    vq_main<<<Nrows / 256, 256, 0, stream>>>(inp, cb, e2p, (const uint4*)cbB,
                                             qout, counts, sse);
    finalize_kernel<<<1, Kc, 0, stream>>>(counts, sse, beta, loss, perp);
}